// Round 2
// baseline (572.273 us; speedup 1.0000x reference)
//
#include <hip/hip_runtime.h>

// KnowldgeShifter: N=32, K=32, T=128, H=768
// Outputs (flat float32, concatenated):
//   score          (N,K)     = 1024      @ 0
//   shifted_encoded(N,T,H)   = 3145728   @ 1024
//   shifted_mask   (N,T)     = 4096      @ 3146752
//   shifted_use    (N,H)     = 24576     @ 3150848
//   shifted_index  (N,T)     = 4096      @ 3175424
// total out_size = 3179520
//
// R1 finding: bool inputs (pool_mask, ck_mask) are materialized as int32
// (4 B/elem) — byte-indexing them produced spurious NEGINF (absmax was
// exactly bf16(1e20)). Cast as const int*.

#define NN 32
#define KK 32
#define TT 128
#define HH 768
#define HH2 1536
#define NEGINF_F (-1e20f)

#define OUT_SCORE 0
#define OUT_ENC   1024
#define OUT_MASK  3146752
#define OUT_USE   3150848
#define OUT_IDX   3175424

// gather work partition (in 0..800767):
//   [0, 786432)        encoded float4 copies
//   [786432, 792576)   use float4 copies
//   [792576, 796672)   mask ints -> float
//   [796672, 800768)   token ints -> float
#define GW_ENC 786432
#define GW_USE 792576
#define GW_MSK 796672
#define GW_TOT 800768

// Kernel 1: blocks [0,48) compute v[n,g] = cqk_pro (2-n register blocking);
//           blocks [48,48+3128) do the label-gather (independent work, fused
//           to overlap BW-bound gather with compute-bound v).
__global__ __launch_bounds__(256) void k1_v_gather(
    const float* __restrict__ ce1,   // (N,3,H)
    const float* __restrict__ tku,   // (N,H)
    const float* __restrict__ pe0,   // (N,K,T,H)
    const float* __restrict__ pe1,   // (N,K,H)
    const int* __restrict__ pmask,   // (N,K,T) bool-as-int32
    const int* __restrict__ label,   // (N,)
    const int* __restrict__ ptok,    // (N,K,T)
    const float* __restrict__ Wcqk,  // (H,2H)
    const float* __restrict__ bcqk,  // (H,)
    float* __restrict__ v,           // ws: (N,H)
    float* __restrict__ out)
{
    int b = blockIdx.x;
    if (b < 48) {
        int t = b * 256 + threadIdx.x;          // 0..12287
        int pair = t / HH;                       // 0..15
        int g = t - pair * HH;                   // 0..767
        int n0 = pair, n1 = pair + 16;
        const float4* wr = (const float4*)(Wcqk + (size_t)g * HH2);
        const float4* q0 = (const float4*)(ce1 + ((size_t)n0 * 3 + 2) * HH);
        const float4* q1 = (const float4*)(ce1 + ((size_t)n1 * 3 + 2) * HH);
        const float4* u0 = (const float4*)(tku + (size_t)n0 * HH);
        const float4* u1 = (const float4*)(tku + (size_t)n1 * HH);
        float a0 = 0.f, a1 = 0.f;
#pragma unroll 4
        for (int j = 0; j < 192; ++j) {          // j-range [0,768): query half
            float4 w4 = wr[j];
            float4 x0 = q0[j];
            float4 x1 = q1[j];
            a0 += w4.x * x0.x + w4.y * x0.y + w4.z * x0.z + w4.w * x0.w;
            a1 += w4.x * x1.x + w4.y * x1.y + w4.z * x1.z + w4.w * x1.w;
        }
#pragma unroll 4
        for (int j = 0; j < 192; ++j) {          // j-range [768,1536): tracked half
            float4 w4 = wr[192 + j];
            float4 x0 = u0[j];
            float4 x1 = u1[j];
            a0 += w4.x * x0.x + w4.y * x0.y + w4.z * x0.z + w4.w * x0.w;
            a1 += w4.x * x1.x + w4.y * x1.y + w4.z * x1.z + w4.w * x1.w;
        }
        float bb = bcqk[g];
        v[n0 * HH + g] = a0 + bb;
        v[n1 * HH + g] = a1 + bb;
    } else {
        int wid = (b - 48) * 256 + threadIdx.x;  // 0..800767 exactly
        if (wid < GW_ENC) {
            // shifted_encoded: float4 copy of pool_encoded_0[n, label[n], :, :]
            int n = wid / 24576;                 // T*H/4 = 24576 float4 per n
            int r = wid - n * 24576;
            int id = label[n];
            float4 val = ((const float4*)pe0)[(size_t)(n * KK + id) * 24576 + r];
            ((float4*)(out + OUT_ENC))[wid] = val;
        } else if (wid < GW_USE) {
            // shifted_use: float4 copy of pool_encoded_1[n, label[n], :]
            int e = wid - GW_ENC;
            int n = e / 192;                     // H/4 = 192 float4 per n
            int r = e - n * 192;
            int id = label[n];
            float4 val = ((const float4*)pe1)[(size_t)(n * KK + id) * 192 + r];
            ((float4*)(out + OUT_USE))[e] = val;
        } else if (wid < GW_MSK) {
            // shifted_mask: int32 bool -> float
            int e = wid - GW_USE;
            int n = e / TT;
            int t = e - n * TT;
            int id = label[n];
            out[OUT_MASK + e] = pmask[(size_t)(n * KK + id) * TT + t] ? 1.0f : 0.0f;
        } else {
            // shifted_index: int -> float (exact, tokens < 2^24)
            int e = wid - GW_MSK;
            int n = e / TT;
            int t = e - n * TT;
            int id = label[n];
            out[OUT_IDX + e] = (float)ptok[(size_t)(n * KK + id) * TT + t];
        }
    }
}

// Kernel 2: w[n,h] = sum_g v[n,g] * W_k[g,h]   (2-n register blocking)
__global__ __launch_bounds__(256) void k2_w(
    const float* __restrict__ Wk,    // (H,H)
    const float* __restrict__ v,     // (N,H)
    float* __restrict__ w)           // ws: (N,H)
{
    int t = blockIdx.x * 256 + threadIdx.x;      // 48 blocks -> 12288
    int pair = t / HH;                           // 0..15
    int h = t - pair * HH;                       // lanes: consecutive h -> coalesced Wk rows
    int n0 = pair, n1 = pair + 16;
    const float4* v0 = (const float4*)(v + (size_t)n0 * HH);
    const float4* v1 = (const float4*)(v + (size_t)n1 * HH);
    float a0 = 0.f, a1 = 0.f;
    for (int g4 = 0; g4 < 192; ++g4) {
        float4 x0 = v0[g4];
        float4 x1 = v1[g4];
        int g = g4 * 4;
        float w0 = Wk[(size_t)(g + 0) * HH + h];
        float w1 = Wk[(size_t)(g + 1) * HH + h];
        float w2 = Wk[(size_t)(g + 2) * HH + h];
        float w3 = Wk[(size_t)(g + 3) * HH + h];
        a0 += x0.x * w0 + x0.y * w1 + x0.z * w2 + x0.w * w3;
        a1 += x1.x * w0 + x1.y * w1 + x1.z * w2 + x1.w * w3;
    }
    w[(size_t)n0 * HH + h] = a0;
    w[(size_t)n1 * HH + h] = a1;
}

// Kernel 3: score[n,k] = ck_mask ? dot(pe1[n,k,:], w[n,:]) + c[n] : NEGINF
// One block per n; c[n] = dot(b_k, v[n,:]) reduced in-block; w[n,:] in LDS.
__global__ __launch_bounds__(256) void k3_score(
    const float* __restrict__ pe1,   // (N,K,H)
    const float* __restrict__ v,     // (N,H)
    const float* __restrict__ w,     // (N,H)
    const float* __restrict__ bk,    // (H,)
    const int* __restrict__ ckm,     // (N,K) bool-as-int32
    float* __restrict__ out)
{
    __shared__ float wl[HH];
    __shared__ float cpart[4];
    int n = blockIdx.x;
    int tid = threadIdx.x;
    int lane = tid & 63;
    int wv = tid >> 6;

    float p = 0.f;
#pragma unroll
    for (int i = 0; i < 3; ++i) {
        int g = tid + 256 * i;
        wl[g] = w[(size_t)n * HH + g];
        p += bk[g] * v[(size_t)n * HH + g];
    }
#pragma unroll
    for (int m = 1; m < 64; m <<= 1) p += __shfl_xor(p, m, 64);
    if (lane == 0) cpart[wv] = p;
    __syncthreads();
    float c = cpart[0] + cpart[1] + cpart[2] + cpart[3];

    for (int k = wv; k < KK; k += 4) {
        const float* row = pe1 + (size_t)(n * KK + k) * HH;
        float acc = 0.f;
#pragma unroll
        for (int i = 0; i < 12; ++i) {
            int h = lane + 64 * i;               // coalesced across lanes
            acc += row[h] * wl[h];
        }
#pragma unroll
        for (int m = 1; m < 64; m <<= 1) acc += __shfl_xor(acc, m, 64);
        if (lane == 0) {
            float s = acc + c;
            out[OUT_SCORE + n * KK + k] = ckm[n * KK + k] ? s : NEGINF_F;
        }
    }
}

extern "C" void kernel_launch(void* const* d_in, const int* in_sizes, int n_in,
                              void* d_out, int out_size, void* d_ws, size_t ws_size,
                              hipStream_t stream)
{
    const float* ce1  = (const float*)d_in[0];
    const float* tku  = (const float*)d_in[1];
    const float* pe0  = (const float*)d_in[2];
    const float* pe1  = (const float*)d_in[3];
    const int* pmask  = (const int*)d_in[4];
    const int* ckm    = (const int*)d_in[5];
    const int* label  = (const int*)d_in[6];
    const int* ptok   = (const int*)d_in[7];
    const float* Wcqk = (const float*)d_in[8];
    const float* bcqk = (const float*)d_in[9];
    const float* Wk   = (const float*)d_in[10];
    const float* bk   = (const float*)d_in[11];

    float* out = (float*)d_out;
    float* v = (float*)d_ws;           // N*H floats
    float* w = v + NN * HH;            // N*H floats  (needs 192 KiB of ws)

    // 48 v-blocks + ceil(800768/256)=3128 gather blocks
    k1_v_gather<<<48 + 3128, 256, 0, stream>>>(ce1, tku, pe0, pe1, pmask,
                                               label, ptok, Wcqk, bcqk, v, out);
    k2_w<<<48, 256, 0, stream>>>(Wk, v, w);
    k3_score<<<32, 256, 0, stream>>>(pe1, v, w, bk, ckm, out);
}